// Round 1
// baseline (824.837 us; speedup 1.0000x reference)
//
#include <hip/hip_runtime.h>

#define A     96
#define DET0  256
#define NZ    32
#define NY    256
#define NX    256
#define T     256
#define LAMB  0.01f

// ws layout (floats):
//   vol_t : [NY][NX][NZ]   = 2,097,152
//   res_t : [A][DET0][NZ]  =   786,432
//   trig  : [A][2]         =       192
#define VOLT_OFF  0
#define REST_OFF  2097152
#define TRIG_OFF  (2097152 + 786432)

// ---------------------------------------------------------------------------
// K1: transpose vol (z,y,x) -> vol_t (y,x,z); also fill trig table.
// grid (NX/64, NY), block 256
__global__ __launch_bounds__(256) void k_transpose(const float* __restrict__ src,
                                                   float* __restrict__ vol_t,
                                                   float* __restrict__ trig) {
    __shared__ float lds[64 * 33];
    const int y   = blockIdx.y;
    const int x0  = blockIdx.x * 64;
    const int tid = threadIdx.x;

    if (blockIdx.x == 0 && y == 0 && tid < A) {
        float th = (float)tid * (float)(3.14159265358979323846 / (double)A);
        trig[2 * tid]     = cosf(th);
        trig[2 * tid + 1] = sinf(th);
    }

    // phase A: coalesced reads over x
    const int xr = tid & 63;
    const int zr = tid >> 6;  // 0..3
    #pragma unroll
    for (int pz = 0; pz < 8; ++pz) {
        int z = pz * 4 + zr;
        lds[xr * 33 + z] = src[(z * NY + y) * NX + x0 + xr];
    }
    __syncthreads();
    // phase B: coalesced writes over (x,z)
    const int zw = tid & 31;
    const int xw = tid >> 5;  // 0..7
    #pragma unroll
    for (int px = 0; px < 8; ++px) {
        int xi = px * 8 + xw;
        vol_t[((size_t)(y * NX + x0 + xi)) * NZ + zw] = lds[xi * 33 + zw];
    }
}

// ---------------------------------------------------------------------------
// K2: res_t[a][u][z] = -p[a*8192 + ((z&7)*4 + (z>>3))*256 + u]
// grid (A), block 256
__global__ __launch_bounds__(256) void k_resinit(const float* __restrict__ p,
                                                 float* __restrict__ res_t) {
    __shared__ float lds[256 * 33];
    const int a = blockIdx.x;
    const int u = threadIdx.x;
    #pragma unroll
    for (int z = 0; z < 32; ++z) {
        int pidx = a * 8192 + (((z & 7) << 2) + (z >> 3)) * 256 + u;
        lds[u * 33 + z] = p[pidx];
    }
    __syncthreads();
    #pragma unroll
    for (int pass = 0; pass < 32; ++pass) {
        int idx = pass * 256 + threadIdx.x;
        int uu  = idx >> 5;
        int z   = idx & 31;
        res_t[a * 8192 + idx] = -lds[uu * 33 + z];
    }
}

// ---------------------------------------------------------------------------
// K3: forward projection; atomically accumulate ray sums into res_t.
// grid (8 t-chunks, A), block 256 (thread = detector u)
__global__ __launch_bounds__(256) void k_forward(const float* __restrict__ vol_t,
                                                 const float* __restrict__ trig,
                                                 float* __restrict__ res_t) {
    const int a = blockIdx.y;
    const int u = threadIdx.x;
    const float c = trig[2 * a];
    const float s = trig[2 * a + 1];
    const float uu = (float)u - 127.5f;
    const float bx = fmaf(-uu, s, 127.5f);  // ix = t*c + bx
    const float by = fmaf(uu, c, 127.5f);   // iy = t*s + by

    float4 acc[8];
    #pragma unroll
    for (int k = 0; k < 8; ++k) acc[k] = make_float4(0.f, 0.f, 0.f, 0.f);

    const int t0 = blockIdx.x * 32;
    #pragma unroll 2
    for (int it = 0; it < 32; ++it) {
        float tt = (float)(t0 + it) - 127.5f;
        float ix = fmaf(tt, c, bx);
        float iy = fmaf(tt, s, by);
        float xf = floorf(ix), yf = floorf(iy);
        float fx = ix - xf, fy = iy - yf;
        int x0 = (int)xf, y0 = (int)yf;

        float wx0 = 1.f - fx, wx1 = fx;
        float wy0 = 1.f - fy, wy1 = fy;
        if ((unsigned)x0 >= NX)       wx0 = 0.f;
        if ((unsigned)(x0 + 1) >= NX) wx1 = 0.f;
        if ((unsigned)y0 >= NY)       wy0 = 0.f;
        if ((unsigned)(y0 + 1) >= NY) wy1 = 0.f;

        // whole-sample skip (outside image): ~50% of the (u,t) grid
        if ((wx0 == 0.f && wx1 == 0.f) || (wy0 == 0.f && wy1 == 0.f)) continue;

        int cx0 = min(max(x0, 0), NX - 1);
        int cx1 = min(max(x0 + 1, 0), NX - 1);
        int cy0 = min(max(y0, 0), NY - 1);
        int cy1 = min(max(y0 + 1, 0), NY - 1);

        float w00 = wy0 * wx0, w01 = wy0 * wx1;
        float w10 = wy1 * wx0, w11 = wy1 * wx1;

        const float4* r00 = (const float4*)(vol_t + (size_t)(cy0 * NX + cx0) * NZ);
        const float4* r01 = (const float4*)(vol_t + (size_t)(cy0 * NX + cx1) * NZ);
        const float4* r10 = (const float4*)(vol_t + (size_t)(cy1 * NX + cx0) * NZ);
        const float4* r11 = (const float4*)(vol_t + (size_t)(cy1 * NX + cx1) * NZ);

        #pragma unroll
        for (int k = 0; k < 8; ++k) {
            float4 v00 = r00[k], v01 = r01[k], v10 = r10[k], v11 = r11[k];
            acc[k].x = fmaf(w00, v00.x, fmaf(w01, v01.x, fmaf(w10, v10.x, fmaf(w11, v11.x, acc[k].x))));
            acc[k].y = fmaf(w00, v00.y, fmaf(w01, v01.y, fmaf(w10, v10.y, fmaf(w11, v11.y, acc[k].y))));
            acc[k].z = fmaf(w00, v00.z, fmaf(w01, v01.z, fmaf(w10, v10.z, fmaf(w11, v11.z, acc[k].z))));
            acc[k].w = fmaf(w00, v00.w, fmaf(w01, v01.w, fmaf(w10, v10.w, fmaf(w11, v11.w, acc[k].w))));
        }
    }

    float* dst = res_t + (size_t)(a * DET0 + u) * NZ;
    #pragma unroll
    for (int k = 0; k < 8; ++k) {
        unsafeAtomicAdd(dst + 4 * k + 0, acc[k].x);
        unsafeAtomicAdd(dst + 4 * k + 1, acc[k].y);
        unsafeAtomicAdd(dst + 4 * k + 2, acc[k].z);
        unsafeAtomicAdd(dst + 4 * k + 3, acc[k].w);
    }
}

// ---------------------------------------------------------------------------
// K4: backprojection of res_t into out = -LAMB * volb, out layout (z,y,x).
// grid (NX/64, NY/4, 2 z-halves), block 256 (64 x × 4 y)
__global__ __launch_bounds__(256) void k_backward(const float* __restrict__ res_t,
                                                  const float* __restrict__ trig,
                                                  float* __restrict__ out) {
    const int tx = threadIdx.x & 63;
    const int ty = threadIdx.x >> 6;
    const int x  = blockIdx.x * 64 + tx;
    const int y  = blockIdx.y * 4 + ty;
    const int zb = blockIdx.z * 16;
    const float xx = (float)x - 127.5f;
    const float yy = (float)y - 127.5f;

    float4 acc[4];
    #pragma unroll
    for (int k = 0; k < 4; ++k) acc[k] = make_float4(0.f, 0.f, 0.f, 0.f);

    for (int a = 0; a < A; ++a) {
        float cc = trig[2 * a];
        float ss = trig[2 * a + 1];
        float ub = fmaf(-xx, ss, fmaf(yy, cc, 127.5f));
        float uf = floorf(ub);
        float fu = ub - uf;
        int i0 = (int)uf;
        float w0 = (1.f - fu) * (((unsigned)i0 < DET0) ? 1.f : 0.f);
        float w1 = fu * (((unsigned)(i0 + 1) < DET0) ? 1.f : 0.f);
        if (w0 == 0.f && w1 == 0.f) continue;
        int c0 = min(max(i0, 0), DET0 - 1);
        int c1 = min(max(i0 + 1, 0), DET0 - 1);
        const float4* r0 = (const float4*)(res_t + (size_t)(a * DET0 + c0) * NZ + zb);
        const float4* r1 = (const float4*)(res_t + (size_t)(a * DET0 + c1) * NZ + zb);
        #pragma unroll
        for (int k = 0; k < 4; ++k) {
            float4 v0 = r0[k], v1 = r1[k];
            acc[k].x = fmaf(w0, v0.x, fmaf(w1, v1.x, acc[k].x));
            acc[k].y = fmaf(w0, v0.y, fmaf(w1, v1.y, acc[k].y));
            acc[k].z = fmaf(w0, v0.z, fmaf(w1, v1.z, acc[k].z));
            acc[k].w = fmaf(w0, v0.w, fmaf(w1, v1.w, acc[k].w));
        }
    }

    #pragma unroll
    for (int k = 0; k < 4; ++k) {
        int z = zb + 4 * k;
        out[(size_t)(z + 0) * (NY * NX) + y * NX + x] = -LAMB * acc[k].x;
        out[(size_t)(z + 1) * (NY * NX) + y * NX + x] = -LAMB * acc[k].y;
        out[(size_t)(z + 2) * (NY * NX) + y * NX + x] = -LAMB * acc[k].z;
        out[(size_t)(z + 3) * (NY * NX) + y * NX + x] = -LAMB * acc[k].w;
    }
}

// ---------------------------------------------------------------------------
extern "C" void kernel_launch(void* const* d_in, const int* in_sizes, int n_in,
                              void* d_out, int out_size, void* d_ws, size_t ws_size,
                              hipStream_t stream) {
    const float* x = (const float*)d_in[0];   // (1,1,32,256,256)
    const float* p = (const float*)d_in[1];   // (1,1,384,8,256)
    float* out = (float*)d_out;               // (1,1,32,256,256)
    float* ws  = (float*)d_ws;

    float* vol_t = ws + VOLT_OFF;
    float* res_t = ws + REST_OFF;
    float* trig  = ws + TRIG_OFF;

    k_transpose<<<dim3(NX / 64, NY), 256, 0, stream>>>(x, vol_t, trig);
    k_resinit  <<<dim3(A), 256, 0, stream>>>(p, res_t);
    k_forward  <<<dim3(8, A), 256, 0, stream>>>(vol_t, trig, res_t);
    k_backward <<<dim3(NX / 64, NY / 4, 2), 256, 0, stream>>>(res_t, trig, out);
}

// Round 2
// 811.690 us; speedup vs baseline: 1.0162x; 1.0162x over previous
//
#include <hip/hip_runtime.h>

#define A     96
#define DET0  256
#define NZ    32
#define NY    256
#define NX    256
#define T     256
#define LAMB  0.01f

// ws layout (floats):
//   vol_t : [NY][NX][NZ]     = 2,097,152
//   res_t : [A][DET0][NZ]    =   786,432
//   trig  : [A][2]           =       192
//   part  : [C][A][DET0][NZ] = C * 786,432   (C = t-chunks, <= 8, ws-dependent)
#define VOLT_OFF  0
#define REST_OFF  2097152
#define TRIG_OFF  (2097152 + 786432)
#define PART_OFF  (2097152 + 786432 + 256)   // 256-float pad keeps 16B alignment
#define RES_ELEMS 786432

// ---------------------------------------------------------------------------
// K1: transpose vol (z,y,x) -> vol_t (y,x,z); also fill trig table.
// grid (NX/64, NY), block 256
__global__ __launch_bounds__(256) void k_transpose(const float* __restrict__ src,
                                                   float* __restrict__ vol_t,
                                                   float* __restrict__ trig) {
    __shared__ float lds[64 * 33];
    const int y   = blockIdx.y;
    const int x0  = blockIdx.x * 64;
    const int tid = threadIdx.x;

    if (blockIdx.x == 0 && y == 0 && tid < A) {
        float th = (float)tid * (float)(3.14159265358979323846 / (double)A);
        trig[2 * tid]     = cosf(th);
        trig[2 * tid + 1] = sinf(th);
    }

    const int xr = tid & 63;
    const int zr = tid >> 6;  // 0..3
    #pragma unroll
    for (int pz = 0; pz < 8; ++pz) {
        int z = pz * 4 + zr;
        lds[xr * 33 + z] = src[(z * NY + y) * NX + x0 + xr];
    }
    __syncthreads();
    const int zw = tid & 31;
    const int xw = tid >> 5;  // 0..7
    #pragma unroll
    for (int px = 0; px < 8; ++px) {
        int xi = px * 8 + xw;
        vol_t[((size_t)(y * NX + x0 + xi)) * NZ + zw] = lds[xi * 33 + zw];
    }
}

// ---------------------------------------------------------------------------
// K2: res_t[a][u][z] = -p[a*8192 + ((z&7)*4 + (z>>3))*256 + u]
// grid (A), block 256
__global__ __launch_bounds__(256) void k_resinit(const float* __restrict__ p,
                                                 float* __restrict__ res_t) {
    __shared__ float lds[256 * 33];
    const int a = blockIdx.x;
    const int u = threadIdx.x;
    #pragma unroll
    for (int z = 0; z < 32; ++z) {
        int pidx = a * 8192 + (((z & 7) << 2) + (z >> 3)) * 256 + u;
        lds[u * 33 + z] = p[pidx];
    }
    __syncthreads();
    #pragma unroll
    for (int pass = 0; pass < 32; ++pass) {
        int idx = pass * 256 + threadIdx.x;
        int uu  = idx >> 5;
        int z   = idx & 31;
        res_t[a * 8192 + idx] = -lds[uu * 33 + z];
    }
}

// ---------------------------------------------------------------------------
// K3: forward projection; each (t-chunk, angle) block writes PRIVATE partial
// sums (no atomics). grid (C, A), block 256 (thread = detector u)
__global__ __launch_bounds__(256) void k_forward(const float* __restrict__ vol_t,
                                                 const float* __restrict__ trig,
                                                 float* __restrict__ part) {
    const int a = blockIdx.y;
    const int u = threadIdx.x;
    const int tlen = T / gridDim.x;
    const int t0 = blockIdx.x * tlen;

    const float c = trig[2 * a];
    const float s = trig[2 * a + 1];
    const float uu = (float)u - 127.5f;
    const float bx = fmaf(-uu, s, 127.5f);  // ix = t*c + bx
    const float by = fmaf(uu, c, 127.5f);   // iy = t*s + by

    float4 acc[8];
    #pragma unroll
    for (int k = 0; k < 8; ++k) acc[k] = make_float4(0.f, 0.f, 0.f, 0.f);

    for (int it = 0; it < tlen; ++it) {
        float tt = (float)(t0 + it) - 127.5f;
        float ix = fmaf(tt, c, bx);
        float iy = fmaf(tt, s, by);
        float xf = floorf(ix), yf = floorf(iy);
        float fx = ix - xf, fy = iy - yf;
        int x0 = (int)xf, y0 = (int)yf;

        float wx0 = 1.f - fx, wx1 = fx;
        float wy0 = 1.f - fy, wy1 = fy;
        if ((unsigned)x0 >= NX)       wx0 = 0.f;
        if ((unsigned)(x0 + 1) >= NX) wx1 = 0.f;
        if ((unsigned)y0 >= NY)       wy0 = 0.f;
        if ((unsigned)(y0 + 1) >= NY) wy1 = 0.f;

        if ((wx0 == 0.f && wx1 == 0.f) || (wy0 == 0.f && wy1 == 0.f)) continue;

        int cx0 = min(max(x0, 0), NX - 1);
        int cx1 = min(max(x0 + 1, 0), NX - 1);
        int cy0 = min(max(y0, 0), NY - 1);
        int cy1 = min(max(y0 + 1, 0), NY - 1);

        float w00 = wy0 * wx0, w01 = wy0 * wx1;
        float w10 = wy1 * wx0, w11 = wy1 * wx1;

        const float4* r00 = (const float4*)(vol_t + (size_t)(cy0 * NX + cx0) * NZ);
        const float4* r01 = (const float4*)(vol_t + (size_t)(cy0 * NX + cx1) * NZ);
        const float4* r10 = (const float4*)(vol_t + (size_t)(cy1 * NX + cx0) * NZ);
        const float4* r11 = (const float4*)(vol_t + (size_t)(cy1 * NX + cx1) * NZ);

        #pragma unroll
        for (int k = 0; k < 8; ++k) {
            float4 v00 = r00[k], v01 = r01[k], v10 = r10[k], v11 = r11[k];
            acc[k].x = fmaf(w00, v00.x, fmaf(w01, v01.x, fmaf(w10, v10.x, fmaf(w11, v11.x, acc[k].x))));
            acc[k].y = fmaf(w00, v00.y, fmaf(w01, v01.y, fmaf(w10, v10.y, fmaf(w11, v11.y, acc[k].y))));
            acc[k].z = fmaf(w00, v00.z, fmaf(w01, v01.z, fmaf(w10, v10.z, fmaf(w11, v11.z, acc[k].z))));
            acc[k].w = fmaf(w00, v00.w, fmaf(w01, v01.w, fmaf(w10, v10.w, fmaf(w11, v11.w, acc[k].w))));
        }
    }

    float4* dst = (float4*)(part + ((size_t)blockIdx.x * RES_ELEMS) +
                            (size_t)(a * DET0 + u) * NZ);
    #pragma unroll
    for (int k = 0; k < 8; ++k) dst[k] = acc[k];
}

// ---------------------------------------------------------------------------
// K3b: res_t += sum_c part[c].  grid (RES_ELEMS/4/256), block 256, float4/thread
__global__ __launch_bounds__(256) void k_combine(const float* __restrict__ part,
                                                 float* __restrict__ res_t,
                                                 int C) {
    const int i = blockIdx.x * 256 + threadIdx.x;  // float4 index
    float4 s = ((const float4*)res_t)[i];
    for (int c = 0; c < C; ++c) {
        float4 v = ((const float4*)(part + (size_t)c * RES_ELEMS))[i];
        s.x += v.x; s.y += v.y; s.z += v.z; s.w += v.w;
    }
    ((float4*)res_t)[i] = s;
}

// ---------------------------------------------------------------------------
// K4: backprojection of res_t into out = -LAMB * volb, out layout (z,y,x).
// grid (NX/64, NY/4, 2 z-halves), block 256 (64 x × 4 y)
__global__ __launch_bounds__(256) void k_backward(const float* __restrict__ res_t,
                                                  const float* __restrict__ trig,
                                                  float* __restrict__ out) {
    const int tx = threadIdx.x & 63;
    const int ty = threadIdx.x >> 6;
    const int x  = blockIdx.x * 64 + tx;
    const int y  = blockIdx.y * 4 + ty;
    const int zb = blockIdx.z * 16;
    const float xx = (float)x - 127.5f;
    const float yy = (float)y - 127.5f;

    float4 acc[4];
    #pragma unroll
    for (int k = 0; k < 4; ++k) acc[k] = make_float4(0.f, 0.f, 0.f, 0.f);

    for (int a = 0; a < A; ++a) {
        float cc = trig[2 * a];
        float ss = trig[2 * a + 1];
        float ub = fmaf(-xx, ss, fmaf(yy, cc, 127.5f));
        float uf = floorf(ub);
        float fu = ub - uf;
        int i0 = (int)uf;
        float w0 = (1.f - fu) * (((unsigned)i0 < DET0) ? 1.f : 0.f);
        float w1 = fu * (((unsigned)(i0 + 1) < DET0) ? 1.f : 0.f);
        if (w0 == 0.f && w1 == 0.f) continue;
        int c0 = min(max(i0, 0), DET0 - 1);
        int c1 = min(max(i0 + 1, 0), DET0 - 1);
        const float4* r0 = (const float4*)(res_t + (size_t)(a * DET0 + c0) * NZ + zb);
        const float4* r1 = (const float4*)(res_t + (size_t)(a * DET0 + c1) * NZ + zb);
        #pragma unroll
        for (int k = 0; k < 4; ++k) {
            float4 v0 = r0[k], v1 = r1[k];
            acc[k].x = fmaf(w0, v0.x, fmaf(w1, v1.x, acc[k].x));
            acc[k].y = fmaf(w0, v0.y, fmaf(w1, v1.y, acc[k].y));
            acc[k].z = fmaf(w0, v0.z, fmaf(w1, v1.z, acc[k].z));
            acc[k].w = fmaf(w0, v0.w, fmaf(w1, v1.w, acc[k].w));
        }
    }

    #pragma unroll
    for (int k = 0; k < 4; ++k) {
        int z = zb + 4 * k;
        out[(size_t)(z + 0) * (NY * NX) + y * NX + x] = -LAMB * acc[k].x;
        out[(size_t)(z + 1) * (NY * NX) + y * NX + x] = -LAMB * acc[k].y;
        out[(size_t)(z + 2) * (NY * NX) + y * NX + x] = -LAMB * acc[k].z;
        out[(size_t)(z + 3) * (NY * NX) + y * NX + x] = -LAMB * acc[k].w;
    }
}

// ---------------------------------------------------------------------------
extern "C" void kernel_launch(void* const* d_in, const int* in_sizes, int n_in,
                              void* d_out, int out_size, void* d_ws, size_t ws_size,
                              hipStream_t stream) {
    const float* x = (const float*)d_in[0];   // (1,1,32,256,256)
    const float* p = (const float*)d_in[1];   // (1,1,384,8,256)
    float* out = (float*)d_out;               // (1,1,32,256,256)
    float* ws  = (float*)d_ws;

    float* vol_t = ws + VOLT_OFF;
    float* res_t = ws + REST_OFF;
    float* trig  = ws + TRIG_OFF;
    float* part  = ws + PART_OFF;

    // choose largest power-of-2 t-chunk count (<=8) whose partials fit in ws
    size_t avail = ws_size / 4 > (size_t)PART_OFF ? ws_size / 4 - PART_OFF : 0;
    int C = 1;
    while (C < 8 && (size_t)(C * 2) * RES_ELEMS <= avail) C *= 2;

    k_transpose<<<dim3(NX / 64, NY), 256, 0, stream>>>(x, vol_t, trig);
    k_resinit  <<<dim3(A), 256, 0, stream>>>(p, res_t);
    k_forward  <<<dim3(C, A), 256, 0, stream>>>(vol_t, trig, part);
    k_combine  <<<dim3(RES_ELEMS / 4 / 256), 256, 0, stream>>>(part, res_t, C);
    k_backward <<<dim3(NX / 64, NY / 4, 2), 256, 0, stream>>>(res_t, trig, out);
}

// Round 3
// 278.162 us; speedup vs baseline: 2.9653x; 2.9181x over previous
//
#include <hip/hip_runtime.h>

#define A     96
#define DET0  256
#define NZ    32
#define NY    256
#define NX    256
#define T     256
#define LAMB  0.01f

// ws layout (floats):
//   trig  : [A][2]            @ 0        (192, padded to 256)
//   res_t : [A][DET0][NZ]     @ 256      (786,432)
//   vol_b : [NY][NX][NZ] bf16 @ 786,688  (2,097,152 ushorts = 1,048,576 floats)
//   part  : [C][A][DET0][NZ]  @ 1,835,264
#define TRIG_OFF  0
#define REST_OFF  256
#define VOLB_OFF  786688
#define PART_OFF  1835264
#define RES_ELEMS 786432

__device__ __forceinline__ unsigned short f2bf_rne(float f) {
    unsigned u = __float_as_uint(f);
    unsigned r = u + 0x7FFF + ((u >> 16) & 1);
    return (unsigned short)(r >> 16);
}
__device__ __forceinline__ float bf2f(unsigned short h) {
    return __uint_as_float((unsigned)h << 16);
}

// ---------------------------------------------------------------------------
// K1: transpose vol (z,y,x) fp32 -> vol_b (y,x,z) bf16; fill trig table.
// grid (NX/64, NY), block 256
__global__ __launch_bounds__(256) void k_transpose(const float* __restrict__ src,
                                                   unsigned short* __restrict__ vol_b,
                                                   float* __restrict__ trig) {
    __shared__ float lds[64 * 33];
    const int y   = blockIdx.y;
    const int x0  = blockIdx.x * 64;
    const int tid = threadIdx.x;

    if (blockIdx.x == 0 && y == 0 && tid < A) {
        float th = (float)tid * (float)(3.14159265358979323846 / (double)A);
        trig[2 * tid]     = cosf(th);
        trig[2 * tid + 1] = sinf(th);
    }

    const int xr = tid & 63;
    const int zr = tid >> 6;  // 0..3
    #pragma unroll
    for (int pz = 0; pz < 8; ++pz) {
        int z = pz * 4 + zr;
        lds[xr * 33 + z] = src[(z * NY + y) * NX + x0 + xr];
    }
    __syncthreads();
    const int zw = tid & 31;
    const int xw = tid >> 5;  // 0..7
    #pragma unroll
    for (int px = 0; px < 8; ++px) {
        int xi = px * 8 + xw;
        vol_b[(y * NX + x0 + xi) * NZ + zw] = f2bf_rne(lds[xi * 33 + zw]);
    }
}

// ---------------------------------------------------------------------------
// K2: res_t[a][u][z] = -p[a*8192 + ((z&7)*4 + (z>>3))*256 + u]
// grid (A), block 256
__global__ __launch_bounds__(256) void k_resinit(const float* __restrict__ p,
                                                 float* __restrict__ res_t) {
    __shared__ float lds[256 * 33];
    const int a = blockIdx.x;
    const int u = threadIdx.x;
    #pragma unroll
    for (int z = 0; z < 32; ++z) {
        int pidx = a * 8192 + (((z & 7) << 2) + (z >> 3)) * 256 + u;
        lds[u * 33 + z] = p[pidx];
    }
    __syncthreads();
    #pragma unroll
    for (int pass = 0; pass < 32; ++pass) {
        int idx = pass * 256 + threadIdx.x;
        int uu  = idx >> 5;
        int z   = idx & 31;
        res_t[a * 8192 + idx] = -lds[uu * 33 + z];
    }
}

// ---------------------------------------------------------------------------
// K3: forward projection, lane = z. Block covers 8 u × tlen t for one angle.
// Phase 1: 8*tlen (u,t) weight/offset entries into LDS + valid-t ranges.
// Phase 2: thread (z, u_sub) accumulates over valid t with coalesced bf16 row
// reads (32 z-lanes = 64 B contiguous). Writes private partials (no atomics).
// grid (32 u-groups, C, A), block 256, dyn LDS = 8*tlen*32 + 64 bytes
__global__ __launch_bounds__(256) void k_forward(const unsigned short* __restrict__ vol_b,
                                                 const float* __restrict__ trig,
                                                 float* __restrict__ part,
                                                 int tlen, int tsh) {
    extern __shared__ char smem[];
    float4* wtab   = (float4*)smem;
    int4*   otab   = (int4*)(smem + (size_t)8 * tlen * 16);
    int*    trange = (int*)(smem + (size_t)8 * tlen * 32);

    const int tid = threadIdx.x;
    const int a  = blockIdx.z;
    const int ug = blockIdx.x;
    const int t0 = blockIdx.y * tlen;

    if (tid < 16) trange[tid] = (tid & 1) ? 0 : tlen;
    __syncthreads();

    const float c = trig[2 * a];
    const float s = trig[2 * a + 1];

    const int nent = 8 * tlen;
    for (int e = tid; e < nent; e += 256) {
        int us = e >> tsh;
        int tt = e & (tlen - 1);
        float uu  = (float)(ug * 8 + us) - 127.5f;
        float ttf = (float)(t0 + tt) - 127.5f;
        float ix = fmaf(ttf, c, fmaf(-uu, s, 127.5f));
        float iy = fmaf(ttf, s, fmaf(uu, c, 127.5f));
        float xf = floorf(ix), yf = floorf(iy);
        float fx = ix - xf, fy = iy - yf;
        int x0 = (int)xf, y0 = (int)yf;
        float wx0 = 1.f - fx, wx1 = fx;
        float wy0 = 1.f - fy, wy1 = fy;
        if ((unsigned)x0 >= NX)       wx0 = 0.f;
        if ((unsigned)(x0 + 1) >= NX) wx1 = 0.f;
        if ((unsigned)y0 >= NY)       wy0 = 0.f;
        if ((unsigned)(y0 + 1) >= NY) wy1 = 0.f;
        bool valid = !((wx0 == 0.f && wx1 == 0.f) || (wy0 == 0.f && wy1 == 0.f));
        int cx0 = min(max(x0, 0), NX - 1);
        int cx1 = min(max(x0 + 1, 0), NX - 1);
        int cy0 = min(max(y0, 0), NY - 1);
        int cy1 = min(max(y0 + 1, 0), NY - 1);
        wtab[e] = make_float4(wy0 * wx0, wy0 * wx1, wy1 * wx0, wy1 * wx1);
        otab[e] = make_int4((cy0 * NX + cx0) * NZ, (cy0 * NX + cx1) * NZ,
                            (cy1 * NX + cx0) * NZ, (cy1 * NX + cx1) * NZ);
        unsigned long long m = __ballot(valid);
        unsigned half = (tid & 32) ? (unsigned)(m >> 32) : (unsigned)m;
        if ((tid & 31) == 0 && half) {
            int lo = tt + (__ffs(half) - 1);
            int hi = tt + (32 - __clz(half));
            atomicMin(&trange[us * 2], lo);
            atomicMax(&trange[us * 2 + 1], hi);
        }
    }
    __syncthreads();

    const int z  = tid & 31;
    const int us = tid >> 5;
    const int lo = trange[us * 2];
    const int hi = trange[us * 2 + 1];
    float acc = 0.f;
    for (int t = lo; t < hi; ++t) {
        float4 w = wtab[us * tlen + t];
        int4   o = otab[us * tlen + t];
        acc = fmaf(w.x, bf2f(vol_b[o.x + z]), acc);
        acc = fmaf(w.y, bf2f(vol_b[o.y + z]), acc);
        acc = fmaf(w.z, bf2f(vol_b[o.z + z]), acc);
        acc = fmaf(w.w, bf2f(vol_b[o.w + z]), acc);
    }
    part[(size_t)blockIdx.y * RES_ELEMS + (a * DET0 + ug * 8 + us) * NZ + z] = acc;
}

// ---------------------------------------------------------------------------
// K3b: res_t += sum_c part[c].  grid (RES_ELEMS/4/256), block 256
__global__ __launch_bounds__(256) void k_combine(const float* __restrict__ part,
                                                 float* __restrict__ res_t,
                                                 int C) {
    const int i = blockIdx.x * 256 + threadIdx.x;  // float4 index
    float4 s = ((const float4*)res_t)[i];
    for (int c = 0; c < C; ++c) {
        float4 v = ((const float4*)(part + (size_t)c * RES_ELEMS))[i];
        s.x += v.x; s.y += v.y; s.z += v.z; s.w += v.w;
    }
    ((float4*)res_t)[i] = s;
}

// ---------------------------------------------------------------------------
// K4: backprojection, lane = z. Block = 8 x-pixels × 1 y × 32 z.
// Phase 1: 768 (a,xs) weight/offset entries into LDS.
// Phase 2: thread (z,xs) loops 96 angles, coalesced res_t row reads.
// grid (NX/8, NY), block 256
__global__ __launch_bounds__(256) void k_backward(const float* __restrict__ res_t,
                                                  const float* __restrict__ trig,
                                                  float* __restrict__ out) {
    __shared__ float4 wb[A * 8];  // 12 KB
    const int tid = threadIdx.x;
    const int y  = blockIdx.y;
    const int xb = blockIdx.x * 8;

    for (int e = tid; e < A * 8; e += 256) {
        int a  = e >> 3;
        int xs = e & 7;
        float cc = trig[2 * a];
        float ss = trig[2 * a + 1];
        float xx = (float)(xb + xs) - 127.5f;
        float yy = (float)y - 127.5f;
        float ub = fmaf(-xx, ss, fmaf(yy, cc, 127.5f));
        float uf = floorf(ub);
        float fu = ub - uf;
        int i0 = (int)uf;
        float w0 = ((unsigned)i0 < DET0) ? (1.f - fu) : 0.f;
        float w1 = ((unsigned)(i0 + 1) < DET0) ? fu : 0.f;
        int c0 = min(max(i0, 0), DET0 - 1);
        int c1 = min(max(i0 + 1, 0), DET0 - 1);
        wb[e] = make_float4(w0, w1,
                            __int_as_float((a * DET0 + c0) * NZ),
                            __int_as_float((a * DET0 + c1) * NZ));
    }
    __syncthreads();

    const int z  = tid & 31;
    const int xs = tid >> 5;
    float acc = 0.f;
    #pragma unroll 4
    for (int a = 0; a < A; ++a) {
        float4 e = wb[a * 8 + xs];
        int o0 = __float_as_int(e.z) + z;
        int o1 = __float_as_int(e.w) + z;
        acc = fmaf(e.x, res_t[o0], fmaf(e.y, res_t[o1], acc));
    }
    out[(size_t)z * (NY * NX) + y * NX + xb + xs] = -LAMB * acc;
}

// ---------------------------------------------------------------------------
extern "C" void kernel_launch(void* const* d_in, const int* in_sizes, int n_in,
                              void* d_out, int out_size, void* d_ws, size_t ws_size,
                              hipStream_t stream) {
    const float* x = (const float*)d_in[0];   // (1,1,32,256,256)
    const float* p = (const float*)d_in[1];   // (1,1,384,8,256)
    float* out = (float*)d_out;               // (1,1,32,256,256)
    float* ws  = (float*)d_ws;

    float*          trig  = ws + TRIG_OFF;
    float*          res_t = ws + REST_OFF;
    unsigned short* vol_b = (unsigned short*)(ws + VOLB_OFF);
    float*          part  = ws + PART_OFF;

    // largest power-of-2 t-chunk count whose partials fit in ws (expect 8)
    size_t avail = ws_size / 4;
    int C = 8;
    while (C > 1 && (size_t)PART_OFF + (size_t)C * RES_ELEMS > avail) C >>= 1;
    int tlen = T / C;
    int tsh  = 31 - __builtin_clz(tlen);
    size_t smem = (size_t)8 * tlen * 32 + 64;

    k_transpose<<<dim3(NX / 64, NY), 256, 0, stream>>>(x, vol_b, trig);
    k_resinit  <<<dim3(A), 256, 0, stream>>>(p, res_t);
    k_forward  <<<dim3(32, C, A), 256, smem, stream>>>(vol_b, trig, part, tlen, tsh);
    k_combine  <<<dim3(RES_ELEMS / 4 / 256), 256, 0, stream>>>(part, res_t, C);
    k_backward <<<dim3(NX / 8, NY), 256, 0, stream>>>(res_t, trig, out);
}

// Round 4
// 205.371 us; speedup vs baseline: 4.0163x; 1.3544x over previous
//
#include <hip/hip_runtime.h>

#define A     96
#define DET0  256
#define NZ    32
#define NY    256
#define NX    256
#define T     256
#define LAMB  0.01f

// ws layout (floats):
//   trig  : [A][2]            @ 0        (192, padded to 256)
//   res_t : [A][DET0][NZ]     @ 256      (786,432)
//   vol_b : [NY][NX][NZ] bf16 @ 786,688  (2,097,152 ushorts = 1,048,576 floats)
//   part  : [C][A][DET0][NZ]  @ 1,835,264
#define TRIG_OFF  0
#define REST_OFF  256
#define VOLB_OFF  786688
#define PART_OFF  1835264
#define RES_ELEMS 786432

__device__ __forceinline__ unsigned short f2bf_rne(float f) {
    unsigned u = __float_as_uint(f);
    unsigned r = u + 0x7FFF + ((u >> 16) & 1);
    return (unsigned short)(r >> 16);
}
__device__ __forceinline__ float blo(unsigned u) { return __uint_as_float(u << 16); }
__device__ __forceinline__ float bhi(unsigned u) { return __uint_as_float(u & 0xFFFF0000u); }

// accumulate 8 bf16 (one vol row segment) * w into acc[0..7]
__device__ __forceinline__ void acc8(float* acc, uint4 q, float w) {
    acc[0] = fmaf(w, blo(q.x), acc[0]); acc[1] = fmaf(w, bhi(q.x), acc[1]);
    acc[2] = fmaf(w, blo(q.y), acc[2]); acc[3] = fmaf(w, bhi(q.y), acc[3]);
    acc[4] = fmaf(w, blo(q.z), acc[4]); acc[5] = fmaf(w, bhi(q.z), acc[5]);
    acc[6] = fmaf(w, blo(q.w), acc[6]); acc[7] = fmaf(w, bhi(q.w), acc[7]);
}

// ---------------------------------------------------------------------------
// K1: transpose vol (z,y,x) fp32 -> vol_b (y,x,z) bf16; fill trig table.
// grid (NX/64, NY), block 256
__global__ __launch_bounds__(256) void k_transpose(const float* __restrict__ src,
                                                   unsigned short* __restrict__ vol_b,
                                                   float* __restrict__ trig) {
    __shared__ float lds[64 * 33];
    const int y   = blockIdx.y;
    const int x0  = blockIdx.x * 64;
    const int tid = threadIdx.x;

    if (blockIdx.x == 0 && y == 0 && tid < A) {
        float th = (float)tid * (float)(3.14159265358979323846 / (double)A);
        trig[2 * tid]     = cosf(th);
        trig[2 * tid + 1] = sinf(th);
    }

    const int xr = tid & 63;
    const int zr = tid >> 6;  // 0..3
    #pragma unroll
    for (int pz = 0; pz < 8; ++pz) {
        int z = pz * 4 + zr;
        lds[xr * 33 + z] = src[(z * NY + y) * NX + x0 + xr];
    }
    __syncthreads();
    const int zw = tid & 31;
    const int xw = tid >> 5;  // 0..7
    #pragma unroll
    for (int px = 0; px < 8; ++px) {
        int xi = px * 8 + xw;
        vol_b[(y * NX + x0 + xi) * NZ + zw] = f2bf_rne(lds[xi * 33 + zw]);
    }
}

// ---------------------------------------------------------------------------
// t-range helper: solve L <= t*g + b <= H for t (tt = t - 127.5 domain)
__device__ __forceinline__ void rng(float g, float b, float L, float H,
                                    float& lo, float& hi) {
    if (fabsf(g) > 1e-5f) {
        float r0 = (L - b) / g, r1 = (H - b) / g;
        lo = fminf(r0, r1); hi = fmaxf(r0, r1);
    } else {
        bool in = (b >= L && b <= H);
        lo = in ? -1e9f : 1e9f;
        hi = in ? 1e9f : -1e9f;
    }
}
__device__ __forceinline__ int clampi(float v) {
    return (int)fminf(fmaxf(v, -2.f), 258.f);
}

// fully-masked edge sample (boundary t's)
__device__ __forceinline__ void sample_edge(const char* base, float ix, float iy,
                                            float* acc) {
    float xf = floorf(ix), yf = floorf(iy);
    float fx = ix - xf, fy = iy - yf;
    int x0 = (int)xf, y0 = (int)yf;
    float wx0 = 1.f - fx, wx1 = fx, wy0 = 1.f - fy, wy1 = fy;
    if ((unsigned)x0 >= NX)       wx0 = 0.f;
    if ((unsigned)(x0 + 1) >= NX) wx1 = 0.f;
    if ((unsigned)y0 >= NY)       wy0 = 0.f;
    if ((unsigned)(y0 + 1) >= NY) wy1 = 0.f;
    if ((wx0 == 0.f && wx1 == 0.f) || (wy0 == 0.f && wy1 == 0.f)) return;
    int cx0 = min(max(x0, 0), NX - 1);
    int cx1 = min(max(x0 + 1, 0), NX - 1);
    int cy0 = min(max(y0, 0), NY - 1);
    int cy1 = min(max(y0 + 1, 0), NY - 1);
    uint4 q00 = *(const uint4*)(base + ((size_t)((cy0 << 8) + cx0) << 6));
    uint4 q01 = *(const uint4*)(base + ((size_t)((cy0 << 8) + cx1) << 6));
    uint4 q10 = *(const uint4*)(base + ((size_t)((cy1 << 8) + cx0) << 6));
    uint4 q11 = *(const uint4*)(base + ((size_t)((cy1 << 8) + cx1) << 6));
    acc8(acc, q00, wy0 * wx0);
    acc8(acc, q01, wy0 * wx1);
    acc8(acc, q10, wy1 * wx0);
    acc8(acc, q11, wy1 * wx1);
}

// ---------------------------------------------------------------------------
// K3: forward projection. thread = (u, z-quarter of 8), no LDS, no atomics.
// Per-thread closed-form valid-t range; mask-free interior loop.
// grid (4 u-groups, C t-chunks, A), block 256
__global__ __launch_bounds__(256) void k_forward(const unsigned short* __restrict__ vol_b,
                                                 const float* __restrict__ trig,
                                                 float* __restrict__ part,
                                                 int tlen) {
    const int tid = threadIdx.x;
    const int a  = blockIdx.z;
    const int u  = blockIdx.x * 64 + (tid >> 2);
    const int zq = tid & 3;                 // 8 z per lane
    const int t0 = blockIdx.y * tlen;

    const float c = trig[2 * a];
    const float s = trig[2 * a + 1];
    const float uu = (float)u - 127.5f;
    const float bx = fmaf(-uu, s, 127.5f);  // ix = tt*c + bx
    const float by = fmaf(uu, c, 127.5f);   // iy = tt*s + by

    // full valid range (contribution possibly nonzero): ix,iy in [-1, 256]
    float lo1, hi1, lo2, hi2;
    rng(c, bx, -1.f, 256.f, lo1, hi1);
    rng(s, by, -1.f, 256.f, lo2, hi2);
    float fl = fmaxf(lo1, lo2), fh = fminf(hi1, hi2);
    int tF0 = max(t0, clampi(ceilf(fl + 127.5f)));
    int tF1 = min(t0 + tlen - 1, clampi(floorf(fh + 127.5f)));
    // strict interior (no clamping/masking needed): ix,iy in [1, 253.5], shrink 1
    rng(c, bx, 1.f, 253.5f, lo1, hi1);
    rng(s, by, 1.f, 253.5f, lo2, hi2);
    float il = fmaxf(lo1, lo2), ih = fminf(hi1, hi2);
    int tI0 = max(clampi(ceilf(il + 127.5f)) + 1, tF0);
    int tI1 = min(clampi(floorf(ih + 127.5f)) - 1, tF1);
    if (tI0 > tI1) { tI0 = tF1 + 1; tI1 = tF1; }

    const char* base = (const char*)vol_b + zq * 16;
    float acc[8];
    #pragma unroll
    for (int k = 0; k < 8; ++k) acc[k] = 0.f;

    for (int t = tF0; t < tI0; ++t) {
        float ttf = (float)t - 127.5f;
        sample_edge(base, fmaf(ttf, c, bx), fmaf(ttf, s, by), acc);
    }
    for (int t = tI0; t <= tI1; ++t) {
        float ttf = (float)t - 127.5f;
        float ix = fmaf(ttf, c, bx);
        float iy = fmaf(ttf, s, by);
        float xf = floorf(ix), yf = floorf(iy);
        float fx = ix - xf, fy = iy - yf;
        int row = ((int)yf << 8) + (int)xf;
        const char* p0 = base + ((size_t)row << 6);
        uint4 q00 = *(const uint4*)(p0);
        uint4 q01 = *(const uint4*)(p0 + 64);
        uint4 q10 = *(const uint4*)(p0 + 16384);
        uint4 q11 = *(const uint4*)(p0 + 16384 + 64);
        float wx0 = 1.f - fx, wy0 = 1.f - fy;
        acc8(acc, q00, wy0 * wx0);
        acc8(acc, q01, wy0 * fx);
        acc8(acc, q10, fy * wx0);
        acc8(acc, q11, fy * fx);
    }
    for (int t = tI1 + 1; t <= tF1; ++t) {
        float ttf = (float)t - 127.5f;
        sample_edge(base, fmaf(ttf, c, bx), fmaf(ttf, s, by), acc);
    }

    float4* dst = (float4*)(part + (size_t)blockIdx.y * RES_ELEMS +
                            ((a * DET0 + u) * NZ + zq * 8));
    dst[0] = make_float4(acc[0], acc[1], acc[2], acc[3]);
    dst[1] = make_float4(acc[4], acc[5], acc[6], acc[7]);
}

// ---------------------------------------------------------------------------
// K3b: res_t = -p_perm + sum_c part[c].  grid (A), block 256
__global__ __launch_bounds__(256) void k_combine(const float* __restrict__ p,
                                                 const float* __restrict__ part,
                                                 float* __restrict__ res_t,
                                                 int C) {
    __shared__ float lds[256 * 33];
    const int a = blockIdx.x;
    const int u = threadIdx.x;
    #pragma unroll
    for (int z = 0; z < 32; ++z) {
        int pidx = a * 8192 + (((z & 7) << 2) + (z >> 3)) * 256 + u;
        lds[u * 33 + z] = p[pidx];
    }
    __syncthreads();
    #pragma unroll
    for (int k = 0; k < 8; ++k) {
        int j4 = k * 256 + threadIdx.x;   // float4 index within this angle
        int j  = j4 * 4;
        int uu = j >> 5;
        int zb = j & 31;
        float4 v = make_float4(-lds[uu * 33 + zb],     -lds[uu * 33 + zb + 1],
                               -lds[uu * 33 + zb + 2], -lds[uu * 33 + zb + 3]);
        for (int c = 0; c < C; ++c) {
            float4 w = ((const float4*)(part + (size_t)c * RES_ELEMS))[a * 2048 + j4];
            v.x += w.x; v.y += w.y; v.z += w.z; v.w += w.w;
        }
        ((float4*)res_t)[a * 2048 + j4] = v;
    }
}

// ---------------------------------------------------------------------------
// K4: backprojection, thread = (x, z-quarter of 4). Weights in LDS per (a,x);
// output re-transposed through LDS for coalesced stores.
// grid (NX/32, NY), block 256
__global__ __launch_bounds__(256) void k_backward(const float* __restrict__ res_t,
                                                  const float* __restrict__ trig,
                                                  float* __restrict__ out) {
    __shared__ float4 wb[A * 32];   // 48 KB: w0, w1, byteoff0, byteoff1
    __shared__ float  ob[32 * 33];  // 4.2 KB output staging
    const int tid = threadIdx.x;
    const int y  = blockIdx.y;
    const int xb = blockIdx.x * 32;

    for (int e = tid; e < A * 32; e += 256) {
        int a  = e >> 5;
        int xs = e & 31;
        float cc = trig[2 * a];
        float ss = trig[2 * a + 1];
        float xx = (float)(xb + xs) - 127.5f;
        float yy = (float)y - 127.5f;
        float ub = fmaf(-xx, ss, fmaf(yy, cc, 127.5f));
        float uf = floorf(ub);
        float fu = ub - uf;
        int i0 = (int)uf;
        float w0 = ((unsigned)i0 < DET0) ? (1.f - fu) : 0.f;
        float w1 = ((unsigned)(i0 + 1) < DET0) ? fu : 0.f;
        int c0 = min(max(i0, 0), DET0 - 1);
        int c1 = min(max(i0 + 1, 0), DET0 - 1);
        wb[e] = make_float4(w0, w1,
                            __int_as_float(((a * DET0 + c0) * NZ) << 2),
                            __int_as_float(((a * DET0 + c1) * NZ) << 2));
    }
    __syncthreads();

    const int xs = tid >> 3;
    const int zq = tid & 7;          // 4 z per lane
    const char* rbase = (const char*)res_t + zq * 16;
    float4 acc = make_float4(0.f, 0.f, 0.f, 0.f);
    #pragma unroll 4
    for (int a = 0; a < A; ++a) {
        float4 e = wb[a * 32 + xs];
        float4 v0 = *(const float4*)(rbase + __float_as_int(e.z));
        float4 v1 = *(const float4*)(rbase + __float_as_int(e.w));
        acc.x = fmaf(e.x, v0.x, fmaf(e.y, v1.x, acc.x));
        acc.y = fmaf(e.x, v0.y, fmaf(e.y, v1.y, acc.y));
        acc.z = fmaf(e.x, v0.z, fmaf(e.y, v1.z, acc.z));
        acc.w = fmaf(e.x, v0.w, fmaf(e.y, v1.w, acc.w));
    }

    ob[(zq * 4 + 0) * 33 + xs] = acc.x;
    ob[(zq * 4 + 1) * 33 + xs] = acc.y;
    ob[(zq * 4 + 2) * 33 + xs] = acc.z;
    ob[(zq * 4 + 3) * 33 + xs] = acc.w;
    __syncthreads();

    const int z  = tid >> 3;
    const int x4 = (tid & 7) * 4;
    float4 o = make_float4(ob[z * 33 + x4],     ob[z * 33 + x4 + 1],
                           ob[z * 33 + x4 + 2], ob[z * 33 + x4 + 3]);
    float4* dst = (float4*)(out + (size_t)z * (NY * NX) + y * NX + xb + x4);
    *dst = make_float4(-LAMB * o.x, -LAMB * o.y, -LAMB * o.z, -LAMB * o.w);
}

// ---------------------------------------------------------------------------
extern "C" void kernel_launch(void* const* d_in, const int* in_sizes, int n_in,
                              void* d_out, int out_size, void* d_ws, size_t ws_size,
                              hipStream_t stream) {
    const float* x = (const float*)d_in[0];   // (1,1,32,256,256)
    const float* p = (const float*)d_in[1];   // (1,1,384,8,256)
    float* out = (float*)d_out;               // (1,1,32,256,256)
    float* ws  = (float*)d_ws;

    float*          trig  = ws + TRIG_OFF;
    float*          res_t = ws + REST_OFF;
    unsigned short* vol_b = (unsigned short*)(ws + VOLB_OFF);
    float*          part  = ws + PART_OFF;

    // largest power-of-2 t-chunk count whose partials fit in ws (expect 8)
    size_t avail = ws_size / 4;
    int C = 8;
    while (C > 1 && (size_t)PART_OFF + (size_t)C * RES_ELEMS > avail) C >>= 1;
    int tlen = T / C;

    k_transpose<<<dim3(NX / 64, NY), 256, 0, stream>>>(x, vol_b, trig);
    k_forward  <<<dim3(4, C, A), 256, 0, stream>>>(vol_b, trig, part, tlen);
    k_combine  <<<dim3(A), 256, 0, stream>>>(p, part, res_t, C);
    k_backward <<<dim3(NX / 32, NY), 256, 0, stream>>>(res_t, trig, out);
}